// Round 8
// baseline (7426.659 us; speedup 1.0000x reference)
//
#include <hip/hip_runtime.h>

typedef short bf16x8 __attribute__((ext_vector_type(8)));
typedef float f32x4 __attribute__((ext_vector_type(4)));
typedef unsigned u32x4 __attribute__((ext_vector_type(4)));

#define T_STEPS 1024
#define NBATCH  64
#define HID     1024
#define NIN     27
#define RINGN   32
#define RINGLO  4
#define LAG     8
#define NGRP    2
#define GWG     64
#define BPG     32
#define NWG     128

#define RINGHI_BYTES ((size_t)RINGN * NBATCH * HID * 2)   // 4 MiB
#define RINGLO_BYTES ((size_t)RINGLO * NBATCH * HID * 2)  // 512 KiB
#define FLAGS_INTS   (NWG * 4 * 16)                       // per-(WG,wave) flags, 64B stride
#define FLAGS_BYTES  ((size_t)FLAGS_INTS * sizeof(int))   // 32 KiB
#define WS_NEED      (RINGHI_BYTES + RINGLO_BYTES + FLAGS_BYTES)

__device__ __forceinline__ unsigned short f2bf(float f) {
    unsigned u = __float_as_uint(f);
    unsigned r = u + 0x7FFFu + ((u >> 16) & 1u);
    return (unsigned short)(r >> 16);
}
__device__ __forceinline__ float bf2f(unsigned short h) {
    return __uint_as_float(((unsigned)h) << 16);
}

// ---- system-coherent (cross-XCD) ops -- the R3-R5-PROVEN primitives ----
__device__ __forceinline__ void ld_b128_sys(const void* p, u32x4& v) {
    asm volatile("global_load_dwordx4 %0, %1, off sc0 sc1" : "=v"(v) : "v"(p));
}
__device__ __forceinline__ void ld_b32_sys(const void* p, unsigned& v) {
    asm volatile("global_load_dword %0, %1, off sc0 sc1" : "=v"(v) : "v"(p));
}
__device__ __forceinline__ int ld_flag_sys(const int* p) {
    int v;
    asm volatile("global_load_dword %0, %1, off sc0 sc1\n\ts_waitcnt vmcnt(0)"
                 : "=v"(v) : "v"(p) : "memory");
    return v;
}
__device__ __forceinline__ void st_b32_sys(void* p, unsigned v) {
    asm volatile("global_store_dword %0, %1, off sc0 sc1" :: "v"(p), "v"(v) : "memory");
}
__device__ __forceinline__ void wait_vm0() {
    asm volatile("s_waitcnt vmcnt(0)" ::: "memory");
    __builtin_amdgcn_sched_barrier(0);   // rule #18: pin consumers below the wait
}
__device__ __forceinline__ void wait_vm8() {
    asm volatile("s_waitcnt vmcnt(8)" ::: "memory");
    __builtin_amdgcn_sched_barrier(0);
}
__device__ __forceinline__ void wait_vm16() {
    asm volatile("s_waitcnt vmcnt(16)" ::: "memory");
    __builtin_amdgcn_sched_barrier(0);
}
__device__ __forceinline__ void wait_vm24() {
    asm volatile("s_waitcnt vmcnt(24)" ::: "memory");
    __builtin_amdgcn_sched_barrier(0);
}

// Persistent GRU: 2 groups x 64 WGs. Group gb owns batches [32gb,32gb+32) as
// two 16-batch A-tiles; WG gs owns hidden cols [16gs,16gs+16). W_hh slice
// (48x1024 bf16) register-resident. h exact in fp32 per-thread; hi/lo bf16
// ring (hi doubles as y_hat history for the fused delayed decode).
// Sync: per-(WG,wave) flags released right after each wave's store drain;
// consumer wave kq polls exactly its 16 producer WGs x 4 waves.
__global__ __launch_bounds__(256, 1)
void gru_persist(const float* __restrict__ x,
                 const int* __restrict__ delays,
                 const float* __restrict__ W_ih,
                 const float* __restrict__ W_hh,
                 const float* __restrict__ b_ih,
                 const float* __restrict__ b_hh,
                 const float* __restrict__ W_dec,
                 float* __restrict__ out,
                 unsigned short* __restrict__ ring_hi,
                 unsigned short* __restrict__ ring_lo,
                 int* __restrict__ flags)
{
    const int tid  = threadIdx.x;
    const int lane = tid & 63;
    const int kq   = tid >> 6;          // wave id = K-quarter (0..3)
    const int gb   = blockIdx.x >> 6;   // group (0..1)
    const int gs   = blockIdx.x & 63;   // j-slice (0..63)
    const int j0   = gs * 16;
    const int l15  = lane & 15;
    const int lhi  = lane >> 4;
    const int Bg   = gb * BPG;

    __shared__ f32x4 red[2][13 * 64];   // per btile: 3 gates x 4 waves + i_n
    __shared__ float ylds[2][512];      // decode y half-row, parity-buffered
    __shared__ float decp[128];         // decode partials [wave][o]
    __shared__ float bias_lds[64];

    // ---- persistent W_hh bf16 fragments: 3 gates x 8 K-chunks ----
    bf16x8 wHH[3][8];
    #pragma unroll
    for (int n = 0; n < 3; ++n) {
        const float* wrow = W_hh + (size_t)(n * HID + j0 + l15) * HID;
        #pragma unroll
        for (int c = 0; c < 8; ++c) {
            const float* wr = wrow + kq * 256 + c * 32 + lhi * 8;
            #pragma unroll
            for (int jj = 0; jj < 8; ++jj) wHH[n][c][jj] = (short)f2bf(wr[jj]);
        }
    }
    bf16x8 wXH[3];
    #pragma unroll
    for (int n = 0; n < 3; ++n) {
        const float* wrow = W_ih + (size_t)(n * HID + j0 + l15) * NIN;
        #pragma unroll
        for (int jj = 0; jj < 8; ++jj) {
            const int kk = lhi * 8 + jj;
            wXH[n][jj] = (kk < NIN) ? (short)f2bf(wrow[kk]) : (short)0;
        }
    }
    if (tid < 16) {
        bias_lds[tid]      = b_ih[j0 + tid] + b_hh[j0 + tid];               // r
        bias_lds[16 + tid] = b_ih[HID + j0 + tid] + b_hh[HID + j0 + tid];   // z
        bias_lds[32 + tid] = b_ih[2 * HID + j0 + tid];                      // n (x side)
        bias_lds[48 + tid] = b_hh[2 * HID + j0 + tid];                      // n (h side)
    }
    // ---- fused decode: batch gs, half qdec=gb (512 cols), W_dec bf16-packed
    const int bdec  = gs;
    const int qdec  = gb;
    const int d_del = delays[bdec];
    const int odec  = tid & 31;
    const int jgd   = tid >> 5;         // 0..7 -> cols [jgd*64, jgd*64+64)
    unsigned wdp[32];
    #pragma unroll
    for (int k = 0; k < 32; ++k) {
        float f0 = 0.f, f1 = 0.f;
        if (odec < NIN) {
            const float* wr = W_dec + (size_t)odec * HID + qdec * 512 + jgd * 64 + 2 * k;
            f0 = wr[0]; f1 = wr[1];
        }
        wdp[k] = (unsigned)f2bf(f0) | ((unsigned)f2bf(f1) << 16);
    }

    const int jl = l15;
    const int bl = kq * 4 + lhi;        // batch-in-tile (0..15)
    const int arow0 = Bg + l15;         // A rows: btile0
    // per-(WG,wave) flags
    int* myflag = flags + (((size_t)blockIdx.x * 4) + kq) * 16;
    // consumer wave kq: producers gs' = kq*16 + (lane&15), wave w = lane>>4
    const int* pollflag = flags
        + (((size_t)(gb * 64 + kq * 16 + (lane & 15)) * 4) + (lane >> 4)) * 16;

    float hprev0 = 0.f, hprev1 = 0.f;
    bool dead = false;

    __syncthreads();

    #pragma clang loop unroll(disable)
    for (int t = 0; t < T_STEPS + LAG; ++t) {
        const int target = (t < T_STEPS) ? t : T_STEPS;
        const int t_dec  = t - LAG;
        const int slot_prev  = (t + RINGN  - 1) & (RINGN  - 1);
        const int slot_prevL = (t + RINGLO - 1) & (RINGLO - 1);

        // ---- (A) decode y load: data >=7 steps old, long visible
        unsigned ydw = 0;
        if (t_dec >= 0) {
            const int tau = (t_dec < d_del) ? t_dec : (t_dec - d_del);
            const unsigned* yrow = (const unsigned*)(ring_hi
                + ((size_t)((tau & (RINGN - 1)) * NBATCH + bdec)) * HID + qdec * 512);
            ld_b32_sys(yrow + tid, ydw);
        }
        // ---- (B) x fragments: wave kq<2 handles btile kq (h-independent)
        bf16x8 axH = {}, axL = {};
        if (t < T_STEPS && kq < 2) {
            const float* xr = x + ((size_t)(Bg + kq * 16 + l15) * T_STEPS + t) * NIN;
            #pragma unroll
            for (int jj = 0; jj < 8; ++jj) {
                const int kk = lhi * 8 + jj;
                if (kk < NIN) {
                    float f = xr[kk];
                    unsigned short hi = f2bf(f);
                    axH[jj] = (short)hi;
                    axL[jj] = (short)f2bf(f - bf2f(hi));
                }
            }
        }
        __builtin_amdgcn_sched_barrier(0);   // compiler x-waits stay above

        // ---- (C) per-wave poll: 16 producer WGs x 4 waves of this K-range
        if (target > 0 && !dead) {
            int iter = 0;
            for (;;) {
                int v = ld_flag_sys(pollflag);
                if (__all(v >= target)) break;
                if (++iter > (1 << 16)) { dead = true; break; }
            }
        }
        wait_vm0();   // free if poll ran; drains y/x stragglers otherwise

        // ---- (D) issue 32 ring loads (b0 hi, b0 lo, b1 hi, b1 lo)
        u32x4 rawH0[8], rawL0[8], rawH1[8], rawL1[8];
        if (t < T_STEPS) {
            const unsigned short* aH0 = ring_hi + ((size_t)(slot_prev  * NBATCH + arow0)) * HID
                                      + kq * 256 + lhi * 8;
            const unsigned short* aL0 = ring_lo + ((size_t)(slot_prevL * NBATCH + arow0)) * HID
                                      + kq * 256 + lhi * 8;
            const unsigned short* aH1 = aH0 + (size_t)16 * HID;   // btile1 rows = +16
            const unsigned short* aL1 = aL0 + (size_t)16 * HID;
            #pragma unroll
            for (int c = 0; c < 8; ++c) ld_b128_sys(aH0 + c * 32, rawH0[c]);
            #pragma unroll
            for (int c = 0; c < 8; ++c) ld_b128_sys(aL0 + c * 32, rawL0[c]);
            #pragma unroll
            for (int c = 0; c < 8; ++c) ld_b128_sys(aH1 + c * 32, rawH1[c]);
            #pragma unroll
            for (int c = 0; c < 8; ++c) ld_b128_sys(aL1 + c * 32, rawL1[c]);
        }

        f32x4 z4 = {0.f, 0.f, 0.f, 0.f};
        f32x4 a00 = z4, a01 = z4, a02 = z4;     // btile0: r,z,n(h)
        f32x4 a10 = z4, a11 = z4, a12 = z4;     // btile1
        f32x4 ax = z4;                           // i_n (x part), waves 0/1

        if (t < T_STEPS) {
            if (kq == 0) {              // x-MFMAs btile0 while loads fly
                a00 = __builtin_amdgcn_mfma_f32_16x16x32_bf16(axH, wXH[0], a00, 0, 0, 0);
                a01 = __builtin_amdgcn_mfma_f32_16x16x32_bf16(axH, wXH[1], a01, 0, 0, 0);
                ax  = __builtin_amdgcn_mfma_f32_16x16x32_bf16(axH, wXH[2], ax, 0, 0, 0);
                a00 = __builtin_amdgcn_mfma_f32_16x16x32_bf16(axL, wXH[0], a00, 0, 0, 0);
                a01 = __builtin_amdgcn_mfma_f32_16x16x32_bf16(axL, wXH[1], a01, 0, 0, 0);
                ax  = __builtin_amdgcn_mfma_f32_16x16x32_bf16(axL, wXH[2], ax, 0, 0, 0);
            } else if (kq == 1) {       // x-MFMAs btile1
                a10 = __builtin_amdgcn_mfma_f32_16x16x32_bf16(axH, wXH[0], a10, 0, 0, 0);
                a11 = __builtin_amdgcn_mfma_f32_16x16x32_bf16(axH, wXH[1], a11, 0, 0, 0);
                ax  = __builtin_amdgcn_mfma_f32_16x16x32_bf16(axH, wXH[2], ax, 0, 0, 0);
                a10 = __builtin_amdgcn_mfma_f32_16x16x32_bf16(axL, wXH[0], a10, 0, 0, 0);
                a11 = __builtin_amdgcn_mfma_f32_16x16x32_bf16(axL, wXH[1], a11, 0, 0, 0);
                ax  = __builtin_amdgcn_mfma_f32_16x16x32_bf16(axL, wXH[2], ax, 0, 0, 0);
            }
            wait_vm24();                // b0 hi done
            #pragma unroll
            for (int c = 0; c < 8; ++c) {
                bf16x8 a = __builtin_bit_cast(bf16x8, rawH0[c]);
                a00 = __builtin_amdgcn_mfma_f32_16x16x32_bf16(a, wHH[0][c], a00, 0, 0, 0);
                a01 = __builtin_amdgcn_mfma_f32_16x16x32_bf16(a, wHH[1][c], a01, 0, 0, 0);
                a02 = __builtin_amdgcn_mfma_f32_16x16x32_bf16(a, wHH[2][c], a02, 0, 0, 0);
            }
            wait_vm16();                // b0 lo done
            #pragma unroll
            for (int c = 0; c < 8; ++c) {
                bf16x8 a = __builtin_bit_cast(bf16x8, rawL0[c]);
                a00 = __builtin_amdgcn_mfma_f32_16x16x32_bf16(a, wHH[0][c], a00, 0, 0, 0);
                a01 = __builtin_amdgcn_mfma_f32_16x16x32_bf16(a, wHH[1][c], a01, 0, 0, 0);
                a02 = __builtin_amdgcn_mfma_f32_16x16x32_bf16(a, wHH[2][c], a02, 0, 0, 0);
            }
            wait_vm8();                 // b1 hi done
            #pragma unroll
            for (int c = 0; c < 8; ++c) {
                bf16x8 a = __builtin_bit_cast(bf16x8, rawH1[c]);
                a10 = __builtin_amdgcn_mfma_f32_16x16x32_bf16(a, wHH[0][c], a10, 0, 0, 0);
                a11 = __builtin_amdgcn_mfma_f32_16x16x32_bf16(a, wHH[1][c], a11, 0, 0, 0);
                a12 = __builtin_amdgcn_mfma_f32_16x16x32_bf16(a, wHH[2][c], a12, 0, 0, 0);
            }
            wait_vm0();                 // b1 lo done
            #pragma unroll
            for (int c = 0; c < 8; ++c) {
                bf16x8 a = __builtin_bit_cast(bf16x8, rawL1[c]);
                a10 = __builtin_amdgcn_mfma_f32_16x16x32_bf16(a, wHH[0][c], a10, 0, 0, 0);
                a11 = __builtin_amdgcn_mfma_f32_16x16x32_bf16(a, wHH[1][c], a11, 0, 0, 0);
                a12 = __builtin_amdgcn_mfma_f32_16x16x32_bf16(a, wHH[2][c], a12, 0, 0, 0);
            }
            red[0][(0 * 4 + kq) * 64 + lane] = a00;
            red[0][(1 * 4 + kq) * 64 + lane] = a01;
            red[0][(2 * 4 + kq) * 64 + lane] = a02;
            red[1][(0 * 4 + kq) * 64 + lane] = a10;
            red[1][(1 * 4 + kq) * 64 + lane] = a11;
            red[1][(2 * 4 + kq) * 64 + lane] = a12;
            if (kq == 0) red[0][12 * 64 + lane] = ax;
            if (kq == 1) red[1][12 * 64 + lane] = ax;
        } else {
            wait_vm0();                 // drain y loads in tail steps
        }
        if (t_dec >= 0) {
            ylds[t & 1][2 * tid]     = bf2f((unsigned short)(ydw & 0xFFFFu));
            ylds[t & 1][2 * tid + 1] = bf2f((unsigned short)(ydw >> 16));
        }
        __syncthreads();   // sync1

        if (t < T_STEPS) {
            // per btile: reduce 4 K-quarters; C layout col=lane&15,row=(lane>>4)*4+reg
            const int ridx = (jl + 16 * (bl >> 2)) * 4 + (bl & 3);
            #pragma unroll
            for (int bt = 0; bt < 2; ++bt) {
                const float* redf = (const float*)&red[bt][0];
                float gr = 0.f, gz = 0.f, gh_n = 0.f;
                #pragma unroll
                for (int w = 0; w < 4; ++w) {
                    gr   += redf[((0 * 4 + w) * 64) * 4 + ridx];
                    gz   += redf[((1 * 4 + w) * 64) * 4 + ridx];
                    gh_n += redf[((2 * 4 + w) * 64) * 4 + ridx];
                }
                const float i_n = redf[(12 * 64) * 4 + ridx];
                const float r  = 1.f / (1.f + __expf(-(gr + bias_lds[jl])));
                const float z  = 1.f / (1.f + __expf(-(gz + bias_lds[16 + jl])));
                const float nn = tanhf(i_n + bias_lds[32 + jl] + r * (gh_n + bias_lds[48 + jl]));
                const float hp = bt ? hprev1 : hprev0;
                const float hnew = (1.f - z) * nn + z * hp;
                if (bt) hprev1 = hnew; else hprev0 = hnew;
                // pack adjacent-j pair into one dword per ring (even lanes store)
                const unsigned short hih = f2bf(hnew);
                const unsigned short loh = f2bf(hnew - bf2f(hih));
                const unsigned nhi = __shfl_xor((unsigned)hih, 1);
                const unsigned nlo = __shfl_xor((unsigned)loh, 1);
                if ((l15 & 1) == 0) {
                    const unsigned dhi = (unsigned)hih | (nhi << 16);
                    const unsigned dlo = (unsigned)loh | (nlo << 16);
                    const int bg = Bg + bt * 16 + bl;
                    unsigned short* ph = ring_hi
                        + ((size_t)((t & (RINGN - 1)) * NBATCH + bg)) * HID + j0 + jl;
                    unsigned short* pl = ring_lo
                        + ((size_t)((t & (RINGLO - 1)) * NBATCH + bg)) * HID + j0 + jl;
                    st_b32_sys(ph, dhi);
                    st_b32_sys(pl, dlo);
                }
            }
        }
        // ---- decode MACs hide under the store drain
        if (t_dec >= 0) {
            float p = 0.f;
            if (odec < NIN) {
                const float* yr = ylds[t & 1] + jgd * 64;
                #pragma unroll
                for (int k = 0; k < 32; ++k) {
                    const unsigned w2 = wdp[k];
                    p += yr[2 * k]     * bf2f((unsigned short)(w2 & 0xFFFFu))
                       + yr[2 * k + 1] * bf2f((unsigned short)(w2 >> 16));
                }
            }
            p += __shfl_xor(p, 32);     // fold jgd pair within the wave
            if (lane < 32) decp[kq * 32 + (lane & 31)] = p;
        }
        wait_vm0();        // this wave's h stores at the coherent point

        if (t < T_STEPS && lane == 0 && !dead)
            st_b32_sys(myflag, (unsigned)(t + 1));   // per-wave release, pre-barrier

        __syncthreads();   // sync2 (decp ready; also fences LDS reuse)

        // ---- tail (shadowed by other WGs' polls): final decode atomics
        if (t_dec >= 0 && tid < NIN) {
            float v = 0.f;
            #pragma unroll
            for (int w = 0; w < 4; ++w) v += decp[w * 32 + tid];
            atomicAdd(out + ((size_t)bdec * T_STEPS + t_dec) * NIN + tid, v);
        }
    }
}

__global__ void fill_out_kernel(float* __restrict__ out, const float* __restrict__ b_dec, int n)
{
    int idx = blockIdx.x * blockDim.x + threadIdx.x;
    if (idx < n) out[idx] = b_dec[idx % NIN];
}

extern "C" void kernel_launch(void* const* d_in, const int* in_sizes, int n_in,
                              void* d_out, int out_size, void* d_ws, size_t ws_size,
                              hipStream_t stream)
{
    (void)in_sizes; (void)n_in;
    const float* xx    = (const float*)d_in[0];
    const int*   dl    = (const int*)d_in[1];
    const float* W_ih  = (const float*)d_in[2];
    const float* W_hh  = (const float*)d_in[3];
    const float* b_ih  = (const float*)d_in[4];
    const float* b_hh  = (const float*)d_in[5];
    const float* W_dec = (const float*)d_in[6];
    const float* b_dec = (const float*)d_in[7];
    float* out = (float*)d_out;

    if (ws_size < WS_NEED) return;

    unsigned short* ring_hi = (unsigned short*)d_ws;
    unsigned short* ring_lo = (unsigned short*)((char*)d_ws + RINGHI_BYTES);
    int*            flags   = (int*)((char*)d_ws + RINGHI_BYTES + RINGLO_BYTES);

    const size_t slot_bytes = (size_t)NBATCH * HID * 2;   // 128 KiB
    // zero h(-1) slots (hi ring slot 31, lo ring slot 3) and flags (R4-proven)
    hipMemsetAsync((char*)d_ws + (size_t)(RINGN - 1) * slot_bytes, 0, slot_bytes, stream);
    hipMemsetAsync((char*)d_ws + RINGHI_BYTES + (size_t)(RINGLO - 1) * slot_bytes, 0,
                   slot_bytes + FLAGS_BYTES, stream);

    fill_out_kernel<<<dim3((out_size + 255) / 256), dim3(256), 0, stream>>>(out, b_dec, out_size);

    void* args[] = {(void*)&xx, (void*)&dl, (void*)&W_ih, (void*)&W_hh, (void*)&b_ih,
                    (void*)&b_hh, (void*)&W_dec, (void*)&out, (void*)&ring_hi,
                    (void*)&ring_lo, (void*)&flags};
    hipError_t e = hipLaunchCooperativeKernel((void*)gru_persist, dim3(NWG), dim3(256),
                                              args, 0, stream);
    if (e != hipSuccess) {
        // plain launch: 128 WGs on 256 CUs are trivially co-resident
        gru_persist<<<dim3(NWG), dim3(256), 0, stream>>>(xx, dl, W_ih, W_hh, b_ih, b_hh,
                                                         W_dec, out, ring_hi, ring_lo, flags);
    }
}

// Round 9
// 5258.262 us; speedup vs baseline: 1.4124x; 1.4124x over previous
//
#include <hip/hip_runtime.h>

typedef short bf16x8 __attribute__((ext_vector_type(8)));
typedef float f32x4 __attribute__((ext_vector_type(4)));
typedef unsigned u32x4 __attribute__((ext_vector_type(4)));

#define T_STEPS 1024
#define NBATCH  64
#define HID     1024
#define NIN     27
#define RINGN   32
#define RINGLO  4
#define LAG     8
#define BPG     16
#define NWG     256

#define RINGHI_BYTES ((size_t)RINGN * NBATCH * HID * 2)   // 4 MiB
#define RINGLO_BYTES ((size_t)RINGLO * NBATCH * HID * 2)  // 512 KiB
#define FLAGS_INTS   (NWG * 4 * 16)                       // per-(WG,wave) flags, 64B stride
#define FLAGS_BYTES  ((size_t)FLAGS_INTS * sizeof(int))   // 64 KiB
#define WS_NEED      (RINGHI_BYTES + RINGLO_BYTES + FLAGS_BYTES)

__device__ __forceinline__ unsigned short f2bf(float f) {
    unsigned u = __float_as_uint(f);
    unsigned r = u + 0x7FFFu + ((u >> 16) & 1u);
    return (unsigned short)(r >> 16);
}
__device__ __forceinline__ float bf2f(unsigned short h) {
    return __uint_as_float(((unsigned)h) << 16);
}

// ---- system-coherent (cross-XCD) ops -- the R3-R5-proven primitives ----
__device__ __forceinline__ void ld_b128_sys(const void* p, u32x4& v) {
    asm volatile("global_load_dwordx4 %0, %1, off sc0 sc1" : "=v"(v) : "v"(p));
}
__device__ __forceinline__ void ld_b32_sys(const void* p, unsigned& v) {
    asm volatile("global_load_dword %0, %1, off sc0 sc1" : "=v"(v) : "v"(p));
}
__device__ __forceinline__ int ld_flag_sys(const int* p) {
    int v;
    asm volatile("global_load_dword %0, %1, off sc0 sc1\n\ts_waitcnt vmcnt(0)"
                 : "=v"(v) : "v"(p) : "memory");
    return v;
}
__device__ __forceinline__ void st_b32_sys(void* p, unsigned v) {
    asm volatile("global_store_dword %0, %1, off sc0 sc1" :: "v"(p), "v"(v) : "memory");
}
__device__ __forceinline__ void wait_vm0() {
    asm volatile("s_waitcnt vmcnt(0)" ::: "memory");
    __builtin_amdgcn_sched_barrier(0);   // rule #18: pin consumers below the wait
}
__device__ __forceinline__ void wait_vm8() {
    asm volatile("s_waitcnt vmcnt(8)" ::: "memory");
    __builtin_amdgcn_sched_barrier(0);
}

// Persistent GRU, R4 geometry + shortened per-step chain:
// 4 groups x 64 WGs; group gb owns batches [16gb,16gb+16); WG gs owns hidden
// cols [16gs,16gs+16). W_hh slice (48x1024 bf16) register-resident. h exact in
// fp32 per-thread; hi/lo bf16 ring (hi doubles as y_hat history for decode).
// ONE barrier/step (LDS parity-buffered); per-wave flag release after own
// store drain; x/y prefetched one step ahead; decode fully in the shadow.
__global__ __launch_bounds__(256, 1)
void gru_persist(const float* __restrict__ x,
                 const int* __restrict__ delays,
                 const float* __restrict__ W_ih,
                 const float* __restrict__ W_hh,
                 const float* __restrict__ b_ih,
                 const float* __restrict__ b_hh,
                 const float* __restrict__ W_dec,
                 float* __restrict__ out,
                 unsigned short* __restrict__ ring_hi,
                 unsigned short* __restrict__ ring_lo,
                 int* __restrict__ flags)
{
    const int tid  = threadIdx.x;
    const int lane = tid & 63;
    const int kq   = tid >> 6;          // wave id = K-quarter (0..3)
    const int gb   = blockIdx.x >> 6;   // batch group (0..3)
    const int gs   = blockIdx.x & 63;   // j-slice (0..63)
    const int j0   = gs * 16;
    const int l15  = lane & 15;
    const int lhi  = lane >> 4;
    const int Bg   = gb * BPG;

    __shared__ f32x4 red[2][13 * 64];   // parity: 3 gates x 4 waves + i_n
    __shared__ float ylds[2][256];      // decode y quarter-row, parity
    __shared__ float decp[2][128];      // decode partials [wave][o], parity
    __shared__ float bias_lds[64];

    // ---- persistent W_hh bf16 fragments: 3 gates x 8 K-chunks ----
    bf16x8 wHH[3][8];
    #pragma unroll
    for (int n = 0; n < 3; ++n) {
        const float* wrow = W_hh + (size_t)(n * HID + j0 + l15) * HID;
        #pragma unroll
        for (int c = 0; c < 8; ++c) {
            const float* wr = wrow + kq * 256 + c * 32 + lhi * 8;
            #pragma unroll
            for (int jj = 0; jj < 8; ++jj) wHH[n][c][jj] = (short)f2bf(wr[jj]);
        }
    }
    bf16x8 wXH[3];
    #pragma unroll
    for (int n = 0; n < 3; ++n) {
        const float* wrow = W_ih + (size_t)(n * HID + j0 + l15) * NIN;
        #pragma unroll
        for (int jj = 0; jj < 8; ++jj) {
            const int kk = lhi * 8 + jj;
            wXH[n][jj] = (kk < NIN) ? (short)f2bf(wrow[kk]) : (short)0;
        }
    }
    if (tid < 16) {
        bias_lds[tid]      = b_ih[j0 + tid] + b_hh[j0 + tid];               // r
        bias_lds[16 + tid] = b_ih[HID + j0 + tid] + b_hh[HID + j0 + tid];   // z
        bias_lds[32 + tid] = b_ih[2 * HID + j0 + tid];                      // n (x side)
        bias_lds[48 + tid] = b_hh[2 * HID + j0 + tid];                      // n (h side)
    }
    // ---- fused decode assignment (R4 scheme) ----
    const int bdec  = gb * BPG + (gs >> 2);
    const int qdec  = gs & 3;
    const int d_del = delays[bdec];
    const int odec  = tid & 31;
    const int jgd   = tid >> 5;
    float wd[32];
    #pragma unroll
    for (int jj = 0; jj < 32; ++jj)
        wd[jj] = (odec < NIN) ? W_dec[(size_t)odec * HID + qdec * 256 + jgd * 32 + jj] : 0.f;

    const int jl = l15;
    const int bl = kq * 4 + lhi;
    const int arow = Bg + l15;          // A-fragment row = batch-in-group

    // per-(WG,wave) flags; consumer wave kq polls its 16 producer WGs x 4 waves
    int* myflag = flags + (((size_t)blockIdx.x * 4) + kq) * 16;
    const int* pollflag = flags
        + (((size_t)(gb * 64 + kq * 16 + (lane >> 2)) * 4) + (lane & 3)) * 16;

    float hprev = 0.f;
    bool dead = false;

    // ---- prefetch state (loop-carried): x fragments for step t, y dword ----
    bf16x8 axH = {}, axL = {};
    if (kq == 0) {                      // build x frags for t = 0
        const float* xr = x + ((size_t)arow * T_STEPS + 0) * NIN;
        #pragma unroll
        for (int jj = 0; jj < 8; ++jj) {
            const int kk = lhi * 8 + jj;
            if (kk < NIN) {
                float f = xr[kk];
                unsigned short hi = f2bf(f);
                axH[jj] = (short)hi;
                axL[jj] = (short)f2bf(f - bf2f(hi));
            }
        }
    }
    unsigned ydw = 0;

    __syncthreads();

    #pragma clang loop unroll(disable)
    for (int t = 0; t <= T_STEPS + LAG; ++t) {
        const int t_dec = t - LAG;
        const int slot_prev  = (t + RINGN  - 1) & (RINGN  - 1);
        const int slot_prevL = (t + RINGLO - 1) & (RINGLO - 1);

        // ---- (C) per-wave poll: first iteration's vmcnt(0) also drains
        // last step's prefetches/flag store (free detection overlap)
        if (t >= 1 && t < T_STEPS && !dead) {
            int iter = 0;
            for (;;) {
                int v = ld_flag_sys(pollflag);
                if (__all(v >= t)) break;
                if (++iter > (1 << 16)) { dead = true; break; }
            }
        } else {
            wait_vm0();   // t==0 / tail: make prefetched regs usable
        }

        // ylds for this step's decode (ydw prefetched last step)
        if (t_dec >= 0 && t_dec < T_STEPS && tid < 128) {
            ylds[t & 1][2 * tid]     = bf2f((unsigned short)(ydw & 0xFFFFu));
            ylds[t & 1][2 * tid + 1] = bf2f((unsigned short)(ydw >> 16));
        }

        // ---- (D) ring loads (8 hi + 8 lo), x-MFMAs under them
        u32x4 rawH[8], rawL[8];
        if (t < T_STEPS) {
            const unsigned short* aH = ring_hi + ((size_t)(slot_prev  * NBATCH + arow)) * HID
                                     + kq * 256 + lhi * 8;
            const unsigned short* aL = ring_lo + ((size_t)(slot_prevL * NBATCH + arow)) * HID
                                     + kq * 256 + lhi * 8;
            #pragma unroll
            for (int c = 0; c < 8; ++c) ld_b128_sys(aH + c * 32, rawH[c]);
            #pragma unroll
            for (int c = 0; c < 8; ++c) ld_b128_sys(aL + c * 32, rawL[c]);
        }

        f32x4 z4 = {0.f, 0.f, 0.f, 0.f};
        f32x4 accA0 = z4, accA1 = z4, accA2 = z4;
        f32x4 accB0 = z4, accB1 = z4, accB2 = z4, acc2x = z4;

        if (t < T_STEPS) {
            if (kq == 0) {              // x-path MFMAs while ring loads fly
                accB0 = __builtin_amdgcn_mfma_f32_16x16x32_bf16(axH, wXH[0], accB0, 0, 0, 0);
                accB1 = __builtin_amdgcn_mfma_f32_16x16x32_bf16(axH, wXH[1], accB1, 0, 0, 0);
                acc2x = __builtin_amdgcn_mfma_f32_16x16x32_bf16(axH, wXH[2], acc2x, 0, 0, 0);
                accB0 = __builtin_amdgcn_mfma_f32_16x16x32_bf16(axL, wXH[0], accB0, 0, 0, 0);
                accB1 = __builtin_amdgcn_mfma_f32_16x16x32_bf16(axL, wXH[1], accB1, 0, 0, 0);
                acc2x = __builtin_amdgcn_mfma_f32_16x16x32_bf16(axL, wXH[2], acc2x, 0, 0, 0);
            }
            wait_vm8();                 // 16 outstanding -> 8 hi loads done
            #pragma unroll
            for (int c = 0; c < 8; ++c) {       // W . h_hi (chain A)
                bf16x8 a = __builtin_bit_cast(bf16x8, rawH[c]);
                accA0 = __builtin_amdgcn_mfma_f32_16x16x32_bf16(a, wHH[0][c], accA0, 0, 0, 0);
                accA1 = __builtin_amdgcn_mfma_f32_16x16x32_bf16(a, wHH[1][c], accA1, 0, 0, 0);
                accA2 = __builtin_amdgcn_mfma_f32_16x16x32_bf16(a, wHH[2][c], accA2, 0, 0, 0);
            }
            wait_vm0();                 // lo loads done
            #pragma unroll
            for (int c = 0; c < 8; ++c) {       // W . h_lo (chain B)
                bf16x8 a = __builtin_bit_cast(bf16x8, rawL[c]);
                accB0 = __builtin_amdgcn_mfma_f32_16x16x32_bf16(a, wHH[0][c], accB0, 0, 0, 0);
                accB1 = __builtin_amdgcn_mfma_f32_16x16x32_bf16(a, wHH[1][c], accB1, 0, 0, 0);
                accB2 = __builtin_amdgcn_mfma_f32_16x16x32_bf16(a, wHH[2][c], accB2, 0, 0, 0);
            }
            red[t & 1][(0 * 4 + kq) * 64 + lane] = accA0 + accB0;
            red[t & 1][(1 * 4 + kq) * 64 + lane] = accA1 + accB1;
            red[t & 1][(2 * 4 + kq) * 64 + lane] = accA2 + accB2;
            if (kq == 0) red[t & 1][12 * 64 + lane] = acc2x;
        }

        __syncthreads();   // the ONLY barrier (vmcnt already 0 -> free drain)

        if (t < T_STEPS) {
            // reduce 4 K-quarter partials; C layout: col=lane&15, row=(lane>>4)*4+reg
            const float* redf = (const float*)&red[t & 1][0];
            const int ridx = (jl + 16 * (bl >> 2)) * 4 + (bl & 3);
            float gr = 0.f, gz = 0.f, gh_n = 0.f;
            #pragma unroll
            for (int w = 0; w < 4; ++w) {
                gr   += redf[((0 * 4 + w) * 64) * 4 + ridx];
                gz   += redf[((1 * 4 + w) * 64) * 4 + ridx];
                gh_n += redf[((2 * 4 + w) * 64) * 4 + ridx];
            }
            const float i_n = redf[(12 * 64) * 4 + ridx];
            const float r  = 1.f / (1.f + __expf(-(gr + bias_lds[jl])));
            const float z  = 1.f / (1.f + __expf(-(gz + bias_lds[16 + jl])));
            const float nn = tanhf(i_n + bias_lds[32 + jl] + r * (gh_n + bias_lds[48 + jl]));
            const float hnew = (1.f - z) * nn + z * hprev;
            hprev = hnew;
            // pack adjacent-j pair into one dword per ring (even lanes store)
            const unsigned short hih = f2bf(hnew);
            const unsigned short loh = f2bf(hnew - bf2f(hih));
            const unsigned nhi = __shfl_xor((unsigned)hih, 1);
            const unsigned nlo = __shfl_xor((unsigned)loh, 1);
            if ((l15 & 1) == 0) {
                const unsigned dhi = (unsigned)hih | (nhi << 16);
                const unsigned dlo = (unsigned)loh | (nlo << 16);
                const int bg = Bg + bl;
                unsigned short* ph = ring_hi
                    + ((size_t)((t & (RINGN - 1)) * NBATCH + bg)) * HID + j0 + jl;
                unsigned short* pl = ring_lo
                    + ((size_t)((t & (RINGLO - 1)) * NBATCH + bg)) * HID + j0 + jl;
                st_b32_sys(ph, dhi);
                st_b32_sys(pl, dlo);
            }
            wait_vm0();                 // this wave's h stores at the coherent pt
            if (lane == 0)
                st_b32_sys(myflag, (unsigned)(t + 1));   // per-wave release
        }

        // ======== shadow region (other WGs are polling) ========
        // decode MACs for t_dec -> decp[t&1]
        if (t_dec >= 0 && t_dec < T_STEPS) {
            float p = 0.f;
            if (odec < NIN) {
                const float* yrow = ylds[t & 1] + jgd * 32;
                #pragma unroll
                for (int k = 0; k < 32; ++k) p += yrow[k] * wd[k];
            }
            p += __shfl_xor(p, 32);
            if (lane < 32) decp[t & 1][kq * 32 + (lane & 31)] = p;
        }
        // final atomics for t_dec-1 (decp written last step; ordered by the
        // barrier this step)
        if (t_dec >= 1 && tid < NIN) {
            const float* dp = decp[(t - 1) & 1];
            float v = dp[tid] + dp[32 + tid] + dp[64 + tid] + dp[96 + tid];
            atomicAdd(out + ((size_t)bdec * T_STEPS + (t_dec - 1)) * NIN + tid, v);
        }
        // y prefetch for next step's t_dec+1
        {
            const int td2 = t_dec + 1;
            if (td2 >= 0 && td2 < T_STEPS && tid < 128) {
                const int tau = (td2 < d_del) ? td2 : (td2 - d_del);
                const unsigned* yrow = (const unsigned*)(ring_hi
                    + ((size_t)((tau & (RINGN - 1)) * NBATCH + bdec)) * HID + qdec * 256);
                ld_b32_sys(yrow + tid, ydw);
            }
        }
        // x fragment build for step t+1 (compiler loads; off critical path)
        if (t + 1 < T_STEPS && kq == 0) {
            const float* xr = x + ((size_t)arow * T_STEPS + (t + 1)) * NIN;
            #pragma unroll
            for (int jj = 0; jj < 8; ++jj) {
                const int kk = lhi * 8 + jj;
                if (kk < NIN) {
                    float f = xr[kk];
                    unsigned short hi = f2bf(f);
                    axH[jj] = (short)hi;
                    axL[jj] = (short)f2bf(f - bf2f(hi));
                } else { axH[jj] = 0; axL[jj] = 0; }
            }
        }
        __builtin_amdgcn_sched_barrier(0);   // keep prefetch waits in this step
    }
}

__global__ void fill_out_kernel(float* __restrict__ out, const float* __restrict__ b_dec, int n)
{
    int idx = blockIdx.x * blockDim.x + threadIdx.x;
    if (idx < n) out[idx] = b_dec[idx % NIN];
}

extern "C" void kernel_launch(void* const* d_in, const int* in_sizes, int n_in,
                              void* d_out, int out_size, void* d_ws, size_t ws_size,
                              hipStream_t stream)
{
    (void)in_sizes; (void)n_in;
    const float* xx    = (const float*)d_in[0];
    const int*   dl    = (const int*)d_in[1];
    const float* W_ih  = (const float*)d_in[2];
    const float* W_hh  = (const float*)d_in[3];
    const float* b_ih  = (const float*)d_in[4];
    const float* b_hh  = (const float*)d_in[5];
    const float* W_dec = (const float*)d_in[6];
    const float* b_dec = (const float*)d_in[7];
    float* out = (float*)d_out;

    if (ws_size < WS_NEED) return;

    unsigned short* ring_hi = (unsigned short*)d_ws;
    unsigned short* ring_lo = (unsigned short*)((char*)d_ws + RINGHI_BYTES);
    int*            flags   = (int*)((char*)d_ws + RINGHI_BYTES + RINGLO_BYTES);

    const size_t slot_bytes = (size_t)NBATCH * HID * 2;   // 128 KiB
    // zero h(-1) slots (hi ring slot 31, lo ring slot 3) and flags
    hipMemsetAsync((char*)d_ws + (size_t)(RINGN - 1) * slot_bytes, 0, slot_bytes, stream);
    hipMemsetAsync((char*)d_ws + RINGHI_BYTES + (size_t)(RINGLO - 1) * slot_bytes, 0,
                   slot_bytes + FLAGS_BYTES, stream);

    fill_out_kernel<<<dim3((out_size + 255) / 256), dim3(256), 0, stream>>>(out, b_dec, out_size);

    void* args[] = {(void*)&xx, (void*)&dl, (void*)&W_ih, (void*)&W_hh, (void*)&b_ih,
                    (void*)&b_hh, (void*)&W_dec, (void*)&out, (void*)&ring_hi,
                    (void*)&ring_lo, (void*)&flags};
    hipError_t e = hipLaunchCooperativeKernel((void*)gru_persist, dim3(NWG), dim3(256),
                                              args, 0, stream);
    if (e != hipSuccess) {
        gru_persist<<<dim3(NWG), dim3(256), 0, stream>>>(xx, dl, W_ih, W_hh, b_ih, b_hh,
                                                         W_dec, out, ring_hi, ring_lo, flags);
    }
}

// Round 10
// 3964.985 us; speedup vs baseline: 1.8731x; 1.3262x over previous
//
#include <hip/hip_runtime.h>

typedef short bf16x8 __attribute__((ext_vector_type(8)));
typedef float f32x4 __attribute__((ext_vector_type(4)));
typedef unsigned u32x4 __attribute__((ext_vector_type(4)));

#define T_STEPS 1024
#define NBATCH  64
#define HID     1024
#define NIN     27
#define RINGN   32
#define LAG     8
#define BPG     16
#define NWG     256

#define RINGHI_BYTES ((size_t)RINGN * NBATCH * HID * 2)   // 4 MiB
#define FLAGS_INTS   (NWG * 16)                           // per-WG flags, 64B stride
#define FLAGS_BYTES  ((size_t)FLAGS_INTS * sizeof(int))   // 16 KiB
#define WS_NEED      (RINGHI_BYTES + FLAGS_BYTES)

__device__ __forceinline__ unsigned short f2bf(float f) {
    unsigned u = __float_as_uint(f);
    unsigned r = u + 0x7FFFu + ((u >> 16) & 1u);
    return (unsigned short)(r >> 16);
}
__device__ __forceinline__ float bf2f(unsigned short h) {
    return __uint_as_float(((unsigned)h) << 16);
}

// ---- system-coherent (cross-XCD) ops -- the R3-R5-proven primitives ----
__device__ __forceinline__ void ld_b128_sys(const void* p, u32x4& v) {
    asm volatile("global_load_dwordx4 %0, %1, off sc0 sc1" : "=v"(v) : "v"(p));
}
__device__ __forceinline__ void ld_b32_sys(const void* p, unsigned& v) {
    asm volatile("global_load_dword %0, %1, off sc0 sc1" : "=v"(v) : "v"(p));
}
__device__ __forceinline__ int ld_flag_sys(const int* p) {
    int v;
    asm volatile("global_load_dword %0, %1, off sc0 sc1\n\ts_waitcnt vmcnt(0)"
                 : "=v"(v) : "v"(p) : "memory");
    return v;
}
__device__ __forceinline__ void st_b32_sys(void* p, unsigned v) {
    asm volatile("global_store_dword %0, %1, off sc0 sc1" :: "v"(p), "v"(v) : "memory");
}
__device__ __forceinline__ void wait_vm0() {
    asm volatile("s_waitcnt vmcnt(0)" ::: "memory");
    __builtin_amdgcn_sched_barrier(0);   // rule #18: pin consumers below the wait
}

// Persistent GRU (R4 structure, single bf16 ring): 4 groups x 64 WGs.
// Group gb owns batches [16gb,16gb+16); WG gs owns hidden cols [16gs,16gs+16).
// W_hh slice (48x1024 bf16) register-resident. h carried EXACT in fp32 per
// thread (ring quantization does not compound); single bf16 ring feeds the
// matmul + fused delayed decode. Poll: each consumer wave waits on exactly
// its 16 K-quarter producer WGs. All cross-WG traffic via sc0/sc1 asm ops.
__global__ __launch_bounds__(256, 1)
void gru_persist(const float* __restrict__ x,
                 const int* __restrict__ delays,
                 const float* __restrict__ W_ih,
                 const float* __restrict__ W_hh,
                 const float* __restrict__ b_ih,
                 const float* __restrict__ b_hh,
                 const float* __restrict__ W_dec,
                 float* __restrict__ out,
                 unsigned short* __restrict__ ring_hi,
                 int* __restrict__ flags)
{
    const int tid  = threadIdx.x;
    const int lane = tid & 63;
    const int kq   = tid >> 6;          // wave id = K-quarter (0..3)
    const int gb   = blockIdx.x >> 6;   // batch group (0..3)
    const int gs   = blockIdx.x & 63;   // j-slice (0..63)
    const int j0   = gs * 16;
    const int l15  = lane & 15;
    const int lhi  = lane >> 4;

    __shared__ f32x4 red[13 * 64];      // 12 = 3 gates x 4 waves, +1 = i_n (x-part)
    __shared__ float ylds[2][256];      // decode y quarter-row, parity-buffered
    __shared__ float bias_lds[64];

    // ---- persistent W_hh bf16 fragments: 3 gates x 8 K-chunks ----
    bf16x8 wHH[3][8];
    #pragma unroll
    for (int n = 0; n < 3; ++n) {
        const float* wrow = W_hh + (size_t)(n * HID + j0 + l15) * HID;
        #pragma unroll
        for (int c = 0; c < 8; ++c) {
            const float* wr = wrow + kq * 256 + c * 32 + lhi * 8;
            #pragma unroll
            for (int jj = 0; jj < 8; ++jj) wHH[n][c][jj] = (short)f2bf(wr[jj]);
        }
    }
    bf16x8 wXH[3];
    #pragma unroll
    for (int n = 0; n < 3; ++n) {
        const float* wrow = W_ih + (size_t)(n * HID + j0 + l15) * NIN;
        #pragma unroll
        for (int jj = 0; jj < 8; ++jj) {
            const int kk = lhi * 8 + jj;
            wXH[n][jj] = (kk < NIN) ? (short)f2bf(wrow[kk]) : (short)0;
        }
    }
    if (tid < 16) {
        bias_lds[tid]      = b_ih[j0 + tid] + b_hh[j0 + tid];               // r
        bias_lds[16 + tid] = b_ih[HID + j0 + tid] + b_hh[HID + j0 + tid];   // z
        bias_lds[32 + tid] = b_ih[2 * HID + j0 + tid];                      // n (x side)
        bias_lds[48 + tid] = b_hh[2 * HID + j0 + tid];                      // n (h side)
    }
    // ---- fused decode assignment ----
    const int bdec  = gb * BPG + (gs >> 2);
    const int qdec  = gs & 3;
    const int d_del = delays[bdec];
    const int odec  = tid & 31;
    const int jgd   = tid >> 5;
    float wd[32];
    #pragma unroll
    for (int jj = 0; jj < 32; ++jj)
        wd[jj] = (odec < NIN) ? W_dec[(size_t)odec * HID + qdec * 256 + jgd * 32 + jj] : 0.f;

    const int jl = l15;
    const int bl = kq * 4 + lhi;
    const int arow = gb * BPG + l15;    // A-fragment row = batch-in-group

    int* myflag = flags + (gb * 64 + gs) * 16;
    // consumer wave kq depends on producers gs' in [16kq, 16kq+16)
    const int* pollflag = flags + (gb * 64 + kq * 16 + l15) * 16;

    float hprev = 0.f;
    bool dead = false;

    __syncthreads();

    #pragma clang loop unroll(disable)
    for (int t = 0; t < T_STEPS + LAG; ++t) {
        const int target = (t < T_STEPS) ? t : T_STEPS;
        const int t_dec  = t - LAG;
        const int slot_prev = (t + RINGN - 1) & (RINGN - 1);

        // ---- (A) decode y-row load: data >=7 steps old, long visible
        unsigned ydw = 0;
        if (t_dec >= 0 && tid < 128) {
            const int tau = (t_dec < d_del) ? t_dec : (t_dec - d_del);
            const unsigned* yrow = (const unsigned*)(ring_hi
                + ((size_t)((tau & (RINGN - 1)) * NBATCH + bdec)) * HID + qdec * 256);
            ld_b32_sys(yrow + tid, ydw);
        }
        // ---- (B) x fragments (wave 0): independent of h, built during the wait
        bf16x8 axH = {}, axL = {};
        if (t < T_STEPS && kq == 0) {
            const float* xr = x + ((size_t)arow * T_STEPS + t) * NIN;
            #pragma unroll
            for (int jj = 0; jj < 8; ++jj) {
                const int kk = lhi * 8 + jj;
                if (kk < NIN) {
                    float f = xr[kk];
                    unsigned short hi = f2bf(f);
                    axH[jj] = (short)hi;
                    axL[jj] = (short)f2bf(f - bf2f(hi));
                }
            }
        }
        __builtin_amdgcn_sched_barrier(0);   // compiler x-waits stay above

        // ---- (C) poll: lanes 0-15 watch this wave's 16 producer WGs
        if (target > 0 && !dead) {
            int iter = 0;
            for (;;) {
                int v = target;
                if (lane < 16) v = ld_flag_sys(pollflag);
                if (__all(v >= target)) break;
                if (++iter > (1 << 16)) { dead = true; break; }
            }
        }
        wait_vm0();   // free if poll ran; covers t==0 / y / x stragglers

        // ---- (D) issue 8 ring loads, overlap x-MFMAs under them
        u32x4 rawH[8];
        if (t < T_STEPS) {
            const unsigned short* aH = ring_hi + ((size_t)(slot_prev * NBATCH + arow)) * HID
                                     + kq * 256 + lhi * 8;
            #pragma unroll
            for (int c = 0; c < 8; ++c) ld_b128_sys(aH + c * 32, rawH[c]);
        }

        f32x4 z4 = {0.f, 0.f, 0.f, 0.f};
        f32x4 acc0 = z4, acc1 = z4, acc2 = z4, acc2x = z4;

        if (t < T_STEPS) {
            if (kq == 0) {              // x-path MFMAs while ring loads fly
                acc0  = __builtin_amdgcn_mfma_f32_16x16x32_bf16(axH, wXH[0], acc0, 0, 0, 0);
                acc1  = __builtin_amdgcn_mfma_f32_16x16x32_bf16(axH, wXH[1], acc1, 0, 0, 0);
                acc2x = __builtin_amdgcn_mfma_f32_16x16x32_bf16(axH, wXH[2], acc2x, 0, 0, 0);
                acc0  = __builtin_amdgcn_mfma_f32_16x16x32_bf16(axL, wXH[0], acc0, 0, 0, 0);
                acc1  = __builtin_amdgcn_mfma_f32_16x16x32_bf16(axL, wXH[1], acc1, 0, 0, 0);
                acc2x = __builtin_amdgcn_mfma_f32_16x16x32_bf16(axL, wXH[2], acc2x, 0, 0, 0);
            }
            wait_vm0();                 // the 8 h loads done
            #pragma unroll
            for (int c = 0; c < 8; ++c) {       // W . h
                bf16x8 a = __builtin_bit_cast(bf16x8, rawH[c]);
                acc0 = __builtin_amdgcn_mfma_f32_16x16x32_bf16(a, wHH[0][c], acc0, 0, 0, 0);
                acc1 = __builtin_amdgcn_mfma_f32_16x16x32_bf16(a, wHH[1][c], acc1, 0, 0, 0);
                acc2 = __builtin_amdgcn_mfma_f32_16x16x32_bf16(a, wHH[2][c], acc2, 0, 0, 0);
            }
            red[(0 * 4 + kq) * 64 + lane] = acc0;
            red[(1 * 4 + kq) * 64 + lane] = acc1;
            red[(2 * 4 + kq) * 64 + lane] = acc2;
            if (kq == 0) red[12 * 64 + lane] = acc2x;
        } else {
            wait_vm0();                 // drain y loads in the tail steps
        }
        if (t_dec >= 0 && tid < 128) {
            ylds[t & 1][2 * tid]     = bf2f((unsigned short)(ydw & 0xFFFFu));
            ylds[t & 1][2 * tid + 1] = bf2f((unsigned short)(ydw >> 16));
        }
        __syncthreads();   // sync1

        if (t < T_STEPS) {
            // reduce 4 K-quarter partials; C layout: col=lane&15, row=(lane>>4)*4+reg
            const float* redf = (const float*)red;
            const int ridx = (jl + 16 * (bl >> 2)) * 4 + (bl & 3);
            float gr = 0.f, gz = 0.f, gh_n = 0.f;
            #pragma unroll
            for (int w = 0; w < 4; ++w) {
                gr   += redf[((0 * 4 + w) * 64) * 4 + ridx];
                gz   += redf[((1 * 4 + w) * 64) * 4 + ridx];
                gh_n += redf[((2 * 4 + w) * 64) * 4 + ridx];
            }
            const float i_n = redf[(12 * 64) * 4 + ridx];
            const float r  = 1.f / (1.f + __expf(-(gr + bias_lds[jl])));
            const float z  = 1.f / (1.f + __expf(-(gz + bias_lds[16 + jl])));
            const float nn = tanhf(i_n + bias_lds[32 + jl] + r * (gh_n + bias_lds[48 + jl]));
            const float hnew = (1.f - z) * nn + z * hprev;
            hprev = hnew;
            // pack adjacent-j pair into one dword (even lanes store)
            const unsigned short hih = f2bf(hnew);
            const unsigned nhi = __shfl_xor((unsigned)hih, 1);
            if ((l15 & 1) == 0) {
                const unsigned dhi = (unsigned)hih | (nhi << 16);
                const int bg = gb * BPG + bl;
                unsigned short* ph = ring_hi
                    + ((size_t)((t & (RINGN - 1)) * NBATCH + bg)) * HID + j0 + jl;
                st_b32_sys(ph, dhi);
            }
        }
        // decode MACs hide here (different waves / same waves post-store)
        float pdec = 0.f;
        if (t_dec >= 0) {
            if (odec < NIN) {
                const float* yrow = ylds[t & 1] + jgd * 32;
                #pragma unroll
                for (int k = 0; k < 32; ++k) pdec += yrow[k] * wd[k];
            }
            pdec += __shfl_xor(pdec, 32);   // fold the wave's two j-groups
        }
        wait_vm0();        // drain own h stores to the coherent point
        __syncthreads();   // sync2: whole WG's h is globally visible

        if (t < T_STEPS && tid == 0 && !dead)
            st_b32_sys(myflag, (unsigned)(t + 1));

        // ---- tail (shadowed by other WGs' polls): decode atomics
        if (t_dec >= 0 && lane < 32 && odec < NIN)
            atomicAdd(out + ((size_t)bdec * T_STEPS + t_dec) * NIN + odec, pdec);
    }
}

__global__ void fill_out_kernel(float* __restrict__ out, const float* __restrict__ b_dec, int n)
{
    int idx = blockIdx.x * blockDim.x + threadIdx.x;
    if (idx < n) out[idx] = b_dec[idx % NIN];
}

extern "C" void kernel_launch(void* const* d_in, const int* in_sizes, int n_in,
                              void* d_out, int out_size, void* d_ws, size_t ws_size,
                              hipStream_t stream)
{
    (void)in_sizes; (void)n_in;
    const float* xx    = (const float*)d_in[0];
    const int*   dl    = (const int*)d_in[1];
    const float* W_ih  = (const float*)d_in[2];
    const float* W_hh  = (const float*)d_in[3];
    const float* b_ih  = (const float*)d_in[4];
    const float* b_hh  = (const float*)d_in[5];
    const float* W_dec = (const float*)d_in[6];
    const float* b_dec = (const float*)d_in[7];
    float* out = (float*)d_out;

    if (ws_size < WS_NEED) return;

    unsigned short* ring_hi = (unsigned short*)d_ws;
    int*            flags   = (int*)((char*)d_ws + RINGHI_BYTES);

    const size_t slot_bytes = (size_t)NBATCH * HID * 2;   // 128 KiB
    // zero h(-1) (ring slot 31) + flags -- contiguous tail region
    hipMemsetAsync((char*)d_ws + (size_t)(RINGN - 1) * slot_bytes, 0,
                   slot_bytes + FLAGS_BYTES, stream);

    fill_out_kernel<<<dim3((out_size + 255) / 256), dim3(256), 0, stream>>>(out, b_dec, out_size);

    void* args[] = {(void*)&xx, (void*)&dl, (void*)&W_ih, (void*)&W_hh, (void*)&b_ih,
                    (void*)&b_hh, (void*)&W_dec, (void*)&out, (void*)&ring_hi, (void*)&flags};
    hipError_t e = hipLaunchCooperativeKernel((void*)gru_persist, dim3(NWG), dim3(256),
                                              args, 0, stream);
    if (e != hipSuccess) {
        gru_persist<<<dim3(NWG), dim3(256), 0, stream>>>(xx, dl, W_ih, W_hh, b_ih, b_hh,
                                                         W_dec, out, ring_hi, flags);
    }
}